// Round 2
// baseline (240.925 us; speedup 1.0000x reference)
//
#include <hip/hip_runtime.h>

// PolicyEncoder: out[n,:] = bias + w_state0[obs0[n]] + w_state1[obs1[n]]
//                          + w_act0[act0[n]] + w_act1[act1[n]]
// N = 262144 rows, D = 128 fp32. Latency-bound random gather + streaming write.
//
// R4: persistent software-pipelined kernel.
//   Evidence: R2/R3 both ~82 µs/dispatch, HBM 42%, VALU 8%, occupancy 76%.
//   Little's law: 256 waves/CU over 197k cycles at 24.5 resident -> ~19k-cycle
//   wave lifetime for ~1.5k cycles of true memory latency. Burst-issue waves
//   drain vmcnt and die; sched_barrier alone couldn't force deeper MLP
//   (VGPR stayed 28 < the 40 needed for 8 live v4f dests).
//   Fix: 2048 persistent blocks (8/CU), 16 iterations per thread, 3-stage
//   pipeline (indices i+2 || gathers i+1 || consume i) with double-buffered
//   gather registers. Data flow now REQUIRES >=8 VMEM in flight per thread
//   at every point; index latency hides under previous gathers; zero
//   launch/drain churn. Full unroll keeps all buffer indices compile-time
//   (runtime-indexed ext_vector arrays would spill to scratch).

#define PE_N 262144
#define PE_D 128
#define PE_BLOCKS 2048
#define PE_THREADS 256
#define ROWS_PER_ITER 8                         // 256 threads / 32 lanes-per-row
#define PE_ITERS (PE_N / (PE_BLOCKS * ROWS_PER_ITER))   // 16

typedef float v4f __attribute__((ext_vector_type(4)));

__global__ __launch_bounds__(PE_THREADS) void PolicyEncoder_79044578116211_kernel(
    const int* __restrict__ obs0, const int* __restrict__ obs1,
    const int* __restrict__ act0, const int* __restrict__ act1,
    const float* __restrict__ w_state0, const float* __restrict__ w_state1,
    const float* __restrict__ w_act0, const float* __restrict__ w_act1,
    const float* __restrict__ bias, float* __restrict__ out)
{
    const int t    = threadIdx.x;
    const int slot = t >> 5;                    // 0..7: row-slot within block
    const int lane = t & 31;                    // float4 index within a row
    const unsigned lofs = (unsigned)lane * 16u; // byte offset within row

    // Block b owns rows [b*128, b*128+128): contiguous 64 KB output span,
    // and its index-array reads live in 4 cache lines per array (L1-hot
    // after iteration 0).
    const int base = blockIdx.x * (ROWS_PER_ITER * PE_ITERS) + slot;

    const v4f xb = *(const v4f*)((const char*)bias + lofs);

    // Double-buffered pipeline state. All indexing below is compile-time
    // (full unroll) so these live in registers, not scratch.
    int i0[2], i1[2], a0[2], a1[2];             // indices for iter parity
    v4f g0[2], g1[2], g2[2], g3[2];             // gather results for iter parity

    // ---- Prologue: indices for iters 0,1; gathers for iter 0. ----
    {
        const int r0 = base;
        i0[0] = obs0[r0]; i1[0] = obs1[r0]; a0[0] = act0[r0]; a1[0] = act1[r0];
        const int r1 = base + ROWS_PER_ITER;
        i0[1] = obs0[r1]; i1[1] = obs1[r1]; a0[1] = act0[r1]; a1[1] = act1[r1];
        // Waits only for the iter-0 index loads (FIFO partial vmcnt);
        // iter-1 indices stay in flight.
        g0[0] = *(const v4f*)((const char*)w_state0 + (((unsigned)i0[0]) << 9) + lofs);
        g1[0] = *(const v4f*)((const char*)w_state1 + (((unsigned)i1[0]) << 9) + lofs);
        g2[0] = *(const v4f*)((const char*)w_act0   + (((unsigned)a0[0]) << 9) + lofs);
        g3[0] = *(const v4f*)((const char*)w_act1   + (((unsigned)a1[0]) << 9) + lofs);
    }

    #pragma unroll
    for (int i = 0; i < PE_ITERS; ++i) {
        const int cur = i & 1;
        const int nxt = (i + 1) & 1;

        // Issue gathers for iter i+1 (needs idx[i+1] arrived -> partial vmcnt
        // wait that leaves gathers[i] in flight).
        if (i + 1 < PE_ITERS) {
            g0[nxt] = *(const v4f*)((const char*)w_state0 + (((unsigned)i0[nxt]) << 9) + lofs);
            g1[nxt] = *(const v4f*)((const char*)w_state1 + (((unsigned)i1[nxt]) << 9) + lofs);
            g2[nxt] = *(const v4f*)((const char*)w_act0   + (((unsigned)a0[nxt]) << 9) + lofs);
            g3[nxt] = *(const v4f*)((const char*)w_act1   + (((unsigned)a1[nxt]) << 9) + lofs);
        }

        // Issue index loads for iter i+2 (overwrites idx[cur], whose values
        // were consumed when gathers[i] were issued).
        if (i + 2 < PE_ITERS) {
            const int r2 = base + (i + 2) * ROWS_PER_ITER;
            i0[cur] = obs0[r2]; i1[cur] = obs1[r2];
            a0[cur] = act0[r2]; a1[cur] = act1[r2];
        }

        // Fence: everything above must be issued before the consume below,
        // so gathers[i+1] + indices[i+2] stay in flight across the wait.
        __builtin_amdgcn_sched_barrier(0);

        // Consume gathers[i] (partial vmcnt retires only the oldest group).
        v4f acc = ((xb + g0[cur]) + (g1[cur] + g2[cur])) + g3[cur];

        v4f* o = (v4f*)((char*)out + (size_t)(base + i * ROWS_PER_ITER) * (PE_D * 4) + lofs);
        __builtin_nontemporal_store(acc, o);
    }
}

extern "C" void kernel_launch(void* const* d_in, const int* in_sizes, int n_in,
                              void* d_out, int out_size, void* d_ws, size_t ws_size,
                              hipStream_t stream) {
    const int*   obs0     = (const int*)  d_in[0];
    const int*   obs1     = (const int*)  d_in[1];
    const int*   act0     = (const int*)  d_in[2];
    const int*   act1     = (const int*)  d_in[3];
    const float* w_state0 = (const float*)d_in[4];
    const float* w_state1 = (const float*)d_in[5];
    const float* w_act0   = (const float*)d_in[6];
    const float* w_act1   = (const float*)d_in[7];
    const float* bias     = (const float*)d_in[8];
    float*       out      = (float*)d_out;

    PolicyEncoder_79044578116211_kernel<<<PE_BLOCKS, PE_THREADS, 0, stream>>>(
        obs0, obs1, act0, act1, w_state0, w_state1, w_act0, w_act1, bias, out);
}

// Round 3
// 236.929 us; speedup vs baseline: 1.0169x; 1.0169x over previous
//
#include <hip/hip_runtime.h>

// PolicyEncoder: out[n,:] = bias + w_state0[obs0[n]] + w_state1[obs1[n]]
//                          + w_act0[act0[n]] + w_act1[act1[n]]
// N = 262144 rows, D = 128 fp32. Random-gather, MSHR/latency-bound.
//
// R5: R2 structure (measured best: 82 µs, VGPR 24) + cache-policy split.
//   Evidence trail: R2 (burst, 76% occ), R3 (+sched_barrier), R4 (persistent
//   2-deep pipeline, VGPR 44, 45% occ) all land at 3.2-3.4 TB/s -> software
//   MLP is NOT the limiter; per-CU miss queue is saturated against the
//   gather latency mix. Remaining lever: lower average latency.
//   - act0/act1 (1 MB total): L2-resident, 262x reuse -> cache normally.
//   - obs1 (25.6 MB, 5.2x reuse): worth caching in L2 -> cache normally.
//   - obs0 (51.2 MB, 2.6x reuse): worst reuse density; its churn evicts
//     obs1/act lines. -> NON-TEMPORAL loads (evict-first, no pollution).
//   Output stores stay non-temporal (write-once streaming).

#define PE_N 262144
#define PE_D 128
#define ROWS_PER_BLOCK 16   // 8 row-slots * 2 rows per thread

typedef float v4f __attribute__((ext_vector_type(4)));

__global__ __launch_bounds__(256) void PolicyEncoder_79044578116211_kernel(
    const int* __restrict__ obs0, const int* __restrict__ obs1,
    const int* __restrict__ act0, const int* __restrict__ act1,
    const float* __restrict__ w_state0, const float* __restrict__ w_state1,
    const float* __restrict__ w_act0, const float* __restrict__ w_act1,
    const float* __restrict__ bias, float* __restrict__ out)
{
    const int t    = threadIdx.x;
    const int slot = t >> 5;          // 0..7 : row-slot within the block
    const int lane = t & 31;          // float4 index within a 128-float row
    const unsigned lofs = (unsigned)lane * 16u;

    const int rowA = blockIdx.x * ROWS_PER_BLOCK + slot;
    const int rowB = rowA + 8;

    // Index loads (lanes within a slot broadcast from the same cache line).
    const int iA0 = obs0[rowA], iB0 = obs0[rowB];
    const int iA1 = obs1[rowA], iB1 = obs1[rowB];
    const int aA0 = act0[rowA], aB0 = act0[rowB];
    const int aA1 = act1[rowA], aB1 = act1[rowB];

    const v4f xb = *(const v4f*)((const char*)bias + lofs);

    // 8 independent gathers. 32-bit byte offsets (idx*512B, max 51.2 MB).
    // obs0 gathers: non-temporal (evict-first) -- 51 MB of ~single-use churn
    // must not evict the high-reuse act/obs1 lines from L1/L2.
    v4f A0 = __builtin_nontemporal_load(
        (const v4f*)((const char*)w_state0 + (((unsigned)iA0) << 9) + lofs));
    v4f B0 = __builtin_nontemporal_load(
        (const v4f*)((const char*)w_state0 + (((unsigned)iB0) << 9) + lofs));
    v4f A1 = *(const v4f*)((const char*)w_state1 + (((unsigned)iA1) << 9) + lofs);
    v4f B1 = *(const v4f*)((const char*)w_state1 + (((unsigned)iB1) << 9) + lofs);
    v4f A2 = *(const v4f*)((const char*)w_act0   + (((unsigned)aA0) << 9) + lofs);
    v4f B2 = *(const v4f*)((const char*)w_act0   + (((unsigned)aB0) << 9) + lofs);
    v4f A3 = *(const v4f*)((const char*)w_act1   + (((unsigned)aA1) << 9) + lofs);
    v4f B3 = *(const v4f*)((const char*)w_act1   + (((unsigned)aB1) << 9) + lofs);

    v4f accA = ((xb + A0) + (A1 + A2)) + A3;
    v4f accB = ((xb + B0) + (B1 + B2)) + B3;

    // Streaming writes: non-temporal so output doesn't evict table rows.
    v4f* outA = (v4f*)((char*)out + (size_t)rowA * (PE_D * 4) + lofs);
    v4f* outB = (v4f*)((char*)out + (size_t)rowB * (PE_D * 4) + lofs);
    __builtin_nontemporal_store(accA, outA);
    __builtin_nontemporal_store(accB, outB);
}

extern "C" void kernel_launch(void* const* d_in, const int* in_sizes, int n_in,
                              void* d_out, int out_size, void* d_ws, size_t ws_size,
                              hipStream_t stream) {
    const int*   obs0     = (const int*)  d_in[0];
    const int*   obs1     = (const int*)  d_in[1];
    const int*   act0     = (const int*)  d_in[2];
    const int*   act1     = (const int*)  d_in[3];
    const float* w_state0 = (const float*)d_in[4];
    const float* w_state1 = (const float*)d_in[5];
    const float* w_act0   = (const float*)d_in[6];
    const float* w_act1   = (const float*)d_in[7];
    const float* bias     = (const float*)d_in[8];
    float*       out      = (float*)d_out;

    const int grid = PE_N / ROWS_PER_BLOCK;  // 16384 blocks
    PolicyEncoder_79044578116211_kernel<<<grid, 256, 0, stream>>>(
        obs0, obs1, act0, act1, w_state0, w_state1, w_act0, w_act1, bias, out);
}

// Round 5
// 234.601 us; speedup vs baseline: 1.0270x; 1.0099x over previous
//
#include <hip/hip_runtime.h>

// PolicyEncoder: out[n,:] = bias + w_state0[obs0[n]] + w_state1[obs1[n]]
//                          + w_act0[act0[n]] + w_act1[act1[n]]
// N = 262144 rows, D = 128 fp32. Random-gather, MSHR/latency-bound.
//
// R7 (= R6 retry, hardened): R5 structure + streaming stores that skip L2.
//   R6 failed with "container failed twice" (no compile error, no counters).
//   Same kernel as R6 except the store drops sc0 (system-scope coherence) --
//   the only plausible in-kernel pathology -- keeping sc1+nt (write past L2,
//   no allocate).
//   Theory (unchanged): R2-R5 all pin at 3.2-3.4 TB/s across 2x concurrency
//   variation -> outstanding-miss budget saturated; avg gather latency is the
//   only lever. FETCH=140 MB vs ~82 MB compulsory: ~58 MB/dispatch of table
//   re-fetch, caused by 131 MB of output stores churning 16.4 MB through each
//   4 MB XCD-L2 (nt alone still allocates). sc1+nt stores leave L2/L3 to the
//   gather working set (act 1 MB, obs1 25.6 MB -> L2; obs tables -> L3).
//   Confirmation signal: FETCH_SIZE -> ~90-110 MB.

#define PE_N 262144
#define PE_D 128
#define ROWS_PER_BLOCK 16   // 8 row-slots * 2 rows per thread

typedef float v4f __attribute__((ext_vector_type(4)));

__device__ __forceinline__ void store_stream(float* p, v4f v) {
    // Streaming store: sc1 (write past L2) + nt (no allocate).
    asm volatile("global_store_dwordx4 %0, %1, off sc1 nt"
                 :: "v"(p), "v"(v) : "memory");
}

__global__ __launch_bounds__(256) void PolicyEncoder_79044578116211_kernel(
    const int* __restrict__ obs0, const int* __restrict__ obs1,
    const int* __restrict__ act0, const int* __restrict__ act1,
    const float* __restrict__ w_state0, const float* __restrict__ w_state1,
    const float* __restrict__ w_act0, const float* __restrict__ w_act1,
    const float* __restrict__ bias, float* __restrict__ out)
{
    const int t    = threadIdx.x;
    const int slot = t >> 5;          // 0..7 : row-slot within the block
    const int lane = t & 31;          // float4 index within a 128-float row
    const unsigned lofs = (unsigned)lane * 16u;

    const int rowA = blockIdx.x * ROWS_PER_BLOCK + slot;
    const int rowB = rowA + 8;

    // Index loads (lanes within a slot broadcast from the same cache line).
    const int iA0 = obs0[rowA], iB0 = obs0[rowB];
    const int iA1 = obs1[rowA], iB1 = obs1[rowB];
    const int aA0 = act0[rowA], aB0 = act0[rowB];
    const int aA1 = act1[rowA], aB1 = act1[rowB];

    const v4f xb = *(const v4f*)((const char*)bias + lofs);

    // 8 independent gathers. 32-bit byte offsets (idx*512B, max 51.2 MB).
    // obs0 gathers non-temporal (evict-first): 51 MB of low-reuse churn
    // shouldn't evict high-reuse act/obs1 lines.
    v4f A0 = __builtin_nontemporal_load(
        (const v4f*)((const char*)w_state0 + (((unsigned)iA0) << 9) + lofs));
    v4f B0 = __builtin_nontemporal_load(
        (const v4f*)((const char*)w_state0 + (((unsigned)iB0) << 9) + lofs));
    v4f A1 = *(const v4f*)((const char*)w_state1 + (((unsigned)iA1) << 9) + lofs);
    v4f B1 = *(const v4f*)((const char*)w_state1 + (((unsigned)iB1) << 9) + lofs);
    v4f A2 = *(const v4f*)((const char*)w_act0   + (((unsigned)aA0) << 9) + lofs);
    v4f B2 = *(const v4f*)((const char*)w_act0   + (((unsigned)aB0) << 9) + lofs);
    v4f A3 = *(const v4f*)((const char*)w_act1   + (((unsigned)aA1) << 9) + lofs);
    v4f B3 = *(const v4f*)((const char*)w_act1   + (((unsigned)aB1) << 9) + lofs);

    v4f accA = ((xb + A0) + (A1 + A2)) + A3;
    v4f accB = ((xb + B0) + (B1 + B2)) + B3;

    // Streaming writes: bypass L2; caches serve gathers only.
    float* outA = (float*)((char*)out + (size_t)rowA * (PE_D * 4) + lofs);
    float* outB = (float*)((char*)out + (size_t)rowB * (PE_D * 4) + lofs);
    store_stream(outA, accA);
    store_stream(outB, accB);
}

extern "C" void kernel_launch(void* const* d_in, const int* in_sizes, int n_in,
                              void* d_out, int out_size, void* d_ws, size_t ws_size,
                              hipStream_t stream) {
    const int*   obs0     = (const int*)  d_in[0];
    const int*   obs1     = (const int*)  d_in[1];
    const int*   act0     = (const int*)  d_in[2];
    const int*   act1     = (const int*)  d_in[3];
    const float* w_state0 = (const float*)d_in[4];
    const float* w_state1 = (const float*)d_in[5];
    const float* w_act0   = (const float*)d_in[6];
    const float* w_act1   = (const float*)d_in[7];
    const float* bias     = (const float*)d_in[8];
    float*       out      = (float*)d_out;

    const int grid = PE_N / ROWS_PER_BLOCK;  // 16384 blocks
    PolicyEncoder_79044578116211_kernel<<<grid, 256, 0, stream>>>(
        obs0, obs1, act0, act1, w_state0, w_state1, w_act0, w_act1, bias, out);
}